// Round 1
// baseline (4127.103 us; speedup 1.0000x reference)
//
#include <hip/hip_runtime.h>
#include <math.h>

#define BATCH 8
#define CH 320
#define HEIGHT 64
#define WIDTH 64
#define HW (HEIGHT*WIDTH)

// workspace layout (bytes)
#define COORD_OFF 1024
#define SAMP_OFF (COORD_OFF + BATCH*HW*6*4)   // 1024 + 786432 = 787456

__device__ __forceinline__ void rodrigues3(float rv0, float rv1, float rv2, float* R) {
    float theta = sqrtf(rv0*rv0 + rv1*rv1 + rv2*rv2);
    float it = 1.0f / fmaxf(theta, 1e-12f);
    float r0 = rv0*it, r1 = rv1*it, r2 = rv2*it;
    float c = cosf(theta), s = sinf(theta), o = 1.0f - c;
    R[0]=c+o*r0*r0;    R[1]=o*r0*r1-s*r2; R[2]=o*r0*r2+s*r1;
    R[3]=o*r1*r0+s*r2; R[4]=c+o*r1*r1;    R[5]=o*r1*r2-s*r0;
    R[6]=o*r2*r0-s*r1; R[7]=o*r2*r1+s*r0; R[8]=c+o*r2*r2;
    if (theta < 1e-6f) {
        R[0]=1;R[1]=0;R[2]=0;R[3]=0;R[4]=1;R[5]=0;R[6]=0;R[7]=0;R[8]=1;
    }
}

__device__ __forceinline__ void inv3(const float* M, float* o) {
    float a=M[0],b=M[1],c=M[2],d=M[3],e=M[4],f=M[5],g=M[6],h=M[7],i=M[8];
    float A = e*i - f*h;
    float B = f*g - d*i;
    float C = d*h - e*g;
    float det = a*A + b*B + c*C;
    float id = 1.0f / det;
    o[0]=A*id;         o[1]=(c*h-b*i)*id; o[2]=(b*f-c*e)*id;
    o[3]=B*id;         o[4]=(a*i-c*g)*id; o[5]=(c*d-a*f)*id;
    o[6]=C*id;         o[7]=(b*g-a*h)*id; o[8]=(a*e-b*d)*id;
}

__global__ void k_fund(const float* __restrict__ Ks, const float* __restrict__ Kt,
                       const float* __restrict__ ps, const float* __restrict__ pt,
                       float* __restrict__ Fout) {
    int b = threadIdx.x;
    if (b >= BATCH) return;
    float Rs[9], Rt[9];
    rodrigues3(ps[b*6+0], ps[b*6+1], ps[b*6+2], Rs);
    rodrigues3(pt[b*6+0], pt[b*6+1], pt[b*6+2], Rt);
    float Rr[9];
    #pragma unroll
    for (int i = 0; i < 3; ++i)
      #pragma unroll
      for (int k = 0; k < 3; ++k)
        Rr[i*3+k] = Rs[i*3+0]*Rt[k*3+0] + Rs[i*3+1]*Rt[k*3+1] + Rs[i*3+2]*Rt[k*3+2];
    float tt0 = pt[b*6+3], tt1 = pt[b*6+4], tt2 = pt[b*6+5];
    float tr0 = ps[b*6+3] - (Rr[0]*tt0 + Rr[1]*tt1 + Rr[2]*tt2);
    float tr1 = ps[b*6+4] - (Rr[3]*tt0 + Rr[4]*tt1 + Rr[5]*tt2);
    float tr2 = ps[b*6+5] - (Rr[6]*tt0 + Rr[7]*tt1 + Rr[8]*tt2);
    float E[9];
    #pragma unroll
    for (int j = 0; j < 3; ++j) {
        E[0*3+j] = -tr2*Rr[1*3+j] + tr1*Rr[2*3+j];
        E[1*3+j] =  tr2*Rr[0*3+j] - tr0*Rr[2*3+j];
        E[2*3+j] = -tr1*Rr[0*3+j] + tr0*Rr[1*3+j];
    }
    float iKs[9], iKt[9];
    inv3(Ks + b*9, iKs);
    inv3(Kt + b*9, iKt);
    float T[9]; // iKt^T @ E
    #pragma unroll
    for (int i = 0; i < 3; ++i)
      #pragma unroll
      for (int k = 0; k < 3; ++k)
        T[i*3+k] = iKt[0*3+i]*E[0*3+k] + iKt[1*3+i]*E[1*3+k] + iKt[2*3+i]*E[2*3+k];
    #pragma unroll
    for (int i = 0; i < 3; ++i)
      #pragma unroll
      for (int l = 0; l < 3; ++l)
        Fout[b*9 + i*3 + l] = T[i*3+0]*iKs[0*3+l] + T[i*3+1]*iKs[1*3+l] + T[i*3+2]*iKs[2*3+l];
}

// per-pixel epipolar sample coordinates: (sx,sy) for 3 samples
__global__ __launch_bounds__(256) void k_coords(const float* __restrict__ Fm,
                                                float* __restrict__ coords) {
    int b = blockIdx.y;
    int k = blockIdx.x * 256 + threadIdx.x;
    const float* F = Fm + b*9;
    float px = (float)(k & 63);
    float py = (float)(k >> 6);
    // lines[i] = F[0][i]*px + F[1][i]*py + F[2][i]   (F^T P)
    float a  = F[0]*px + F[3]*py + F[6];
    float bb = F[1]*px + F[4]*py + F[7];
    float c  = F[2]*px + F[5]*py + F[8];
    const float EPS = 1e-10f, W1 = 63.0f, H1 = 63.0f;
    float x1 = fminf(fmaxf(-c/(a+EPS), 0.0f), W1);
    float x2 = fminf(fmaxf(-(bb*H1+c)/(a+EPS), 0.0f), W1);
    float y1 = fminf(fmaxf(-c/(bb+EPS), 0.0f), H1);
    float y2 = fminf(fmaxf(-(a*W1+c)/(bb+EPS), 0.0f), H1);
    float* o = coords + ((size_t)b*HW + k)*6;
    o[0] = x1;                 o[1] = y1;
    o[2] = 0.5f*x1 + 0.5f*x2;  o[3] = 0.5f*y1 + 0.5f*y2;
    o[4] = x2;                 o[5] = y2;
}

// bilinear sample + mean over 3 samples; one (b,c) 16KB plane per block in LDS
__global__ __launch_bounds__(256) void k_sample(const float* __restrict__ x,
                                                const float* __restrict__ coords,
                                                float* __restrict__ samp) {
    __shared__ float plane[HW];
    int c = blockIdx.x, b = blockIdx.y;
    const float4* src4 = (const float4*)(x + ((size_t)(b*CH + c))*HW);
    float4* p4 = (float4*)plane;
    #pragma unroll
    for (int i = 0; i < 4; ++i) p4[threadIdx.x + i*256] = src4[threadIdx.x + i*256];
    __syncthreads();
    const float* cbase = coords + (size_t)b*HW*6;
    float* outp = samp + ((size_t)(b*CH + c))*HW;
    #pragma unroll
    for (int i = 0; i < HW/256; ++i) {
        int k = threadIdx.x + i*256;
        const float* cc = cbase + (size_t)k*6;
        float acc = 0.0f;
        #pragma unroll
        for (int s = 0; s < 3; ++s) {
            float sx = cc[s*2+0], sy = cc[s*2+1];
            float fx0 = floorf(sx), fy0 = floorf(sy);
            float wx = sx - fx0, wy = sy - fy0;
            int x0 = (int)fx0, y0 = (int)fy0;
            int x1 = min(x0+1, 63), y1 = min(y0+1, 63);
            float g00 = plane[y0*64+x0], g10 = plane[y0*64+x1];
            float g01 = plane[y1*64+x0], g11 = plane[y1*64+x1];
            acc += (g00*(1.0f-wx) + g10*wx)*(1.0f-wy) + (g01*(1.0f-wx) + g11*wx)*wy;
        }
        outp[k] = acc * (1.0f/3.0f);
    }
}

// 3x3 SAME conv + bias + relu. Block: 32x32 spatial tile x 8 output channels.
// 4 input channels staged in LDS per step; each thread computes 2x2 outputs.
#define G 8
#define CPI 4
#define TDIM 34
#define TSZ (TDIM*TDIM)

__global__ __launch_bounds__(256) void k_conv(const float* __restrict__ samp,
                                              const float* __restrict__ wgt,
                                              const float* __restrict__ bias,
                                              float* __restrict__ out) {
    __shared__ float tile[CPI*TSZ];   // 18496 B
    int tileId = blockIdx.x;          // 0..3
    int cg = blockIdx.y;              // 0..39
    int b  = blockIdx.z;
    int ty0 = (tileId >> 1) * 32, tx0 = (tileId & 1) * 32;
    int tx = threadIdx.x & 15, ty = threadIdx.x >> 4;
    int co0 = cg * G;
    float acc[G][4];
    #pragma unroll
    for (int g = 0; g < G; ++g) { acc[g][0]=0.f; acc[g][1]=0.f; acc[g][2]=0.f; acc[g][3]=0.f; }
    int base = (2*ty)*TDIM + 2*tx;
    for (int ci0 = 0; ci0 < CH; ci0 += CPI) {
        __syncthreads();
        #pragma unroll
        for (int p = 0; p < CPI; ++p) {
            const float* plane = samp + ((size_t)(b*CH + ci0 + p))*HW;
            for (int idx = threadIdx.x; idx < TSZ; idx += 256) {
                int r = idx / TDIM, cc2 = idx - r*TDIM;
                int gy = ty0 + r - 1, gx = tx0 + cc2 - 1;
                float v = 0.0f;
                if ((unsigned)gy < 64u && (unsigned)gx < 64u) v = plane[gy*64 + gx];
                tile[p*TSZ + idx] = v;
            }
        }
        __syncthreads();
        #pragma unroll
        for (int p = 0; p < CPI; ++p) {
            const float* tb = tile + p*TSZ + base;
            float t00=tb[0],  t01=tb[1],  t02=tb[2],  t03=tb[3];
            float t10=tb[34], t11=tb[35], t12=tb[36], t13=tb[37];
            float t20=tb[68], t21=tb[69], t22=tb[70], t23=tb[71];
            float t30=tb[102],t31=tb[103],t32=tb[104],t33=tb[105];
            int ci = ci0 + p;
            #pragma unroll
            for (int g = 0; g < G; ++g) {
                const float* wp = wgt + ((size_t)(co0+g)*CH + ci)*9;
                float w0=wp[0],w1=wp[1],w2=wp[2],w3=wp[3],w4=wp[4],w5=wp[5],w6=wp[6],w7=wp[7],w8=wp[8];
                acc[g][0] += w0*t00+w1*t01+w2*t02 + w3*t10+w4*t11+w5*t12 + w6*t20+w7*t21+w8*t22;
                acc[g][1] += w0*t01+w1*t02+w2*t03 + w3*t11+w4*t12+w5*t13 + w6*t21+w7*t22+w8*t23;
                acc[g][2] += w0*t10+w1*t11+w2*t12 + w3*t20+w4*t21+w5*t22 + w6*t30+w7*t31+w8*t32;
                acc[g][3] += w0*t11+w1*t12+w2*t13 + w3*t21+w4*t22+w5*t23 + w6*t31+w7*t32+w8*t33;
            }
        }
    }
    int oy = ty0 + 2*ty, ox = tx0 + 2*tx;
    #pragma unroll
    for (int g = 0; g < G; ++g) {
        float bv = bias[co0 + g];
        float* ob = out + ((size_t)(b*CH + co0 + g))*HW + oy*64 + ox;
        ob[0]  = fmaxf(acc[g][0] + bv, 0.0f);
        ob[1]  = fmaxf(acc[g][1] + bv, 0.0f);
        ob[64] = fmaxf(acc[g][2] + bv, 0.0f);
        ob[65] = fmaxf(acc[g][3] + bv, 0.0f);
    }
}

extern "C" void kernel_launch(void* const* d_in, const int* in_sizes, int n_in,
                              void* d_out, int out_size, void* d_ws, size_t ws_size,
                              hipStream_t stream) {
    const float* x  = (const float*)d_in[0];
    const float* Ks = (const float*)d_in[1];
    const float* Kt = (const float*)d_in[2];
    const float* ps = (const float*)d_in[3];
    const float* pt = (const float*)d_in[4];
    const float* cw = (const float*)d_in[5];
    const float* cb = (const float*)d_in[6];
    float* out = (float*)d_out;
    char* ws = (char*)d_ws;
    float* F      = (float*)(ws);
    float* coords = (float*)(ws + COORD_OFF);
    float* samp   = (float*)(ws + SAMP_OFF);

    k_fund<<<1, 64, 0, stream>>>(Ks, Kt, ps, pt, F);
    k_coords<<<dim3(HW/256, BATCH), 256, 0, stream>>>(F, coords);
    k_sample<<<dim3(CH, BATCH), 256, 0, stream>>>(x, coords, samp);
    k_conv<<<dim3(4, CH/G, BATCH), 256, 0, stream>>>(samp, cw, cb, out);
}

// Round 3
// 179.940 us; speedup vs baseline: 22.9360x; 22.9360x over previous
//
#include <hip/hip_runtime.h>
#include <math.h>

#define BATCH 8
#define CH 320
#define HW 4096

typedef unsigned short u16;
typedef __attribute__((ext_vector_type(8))) short bf16x8;
typedef __attribute__((ext_vector_type(8))) unsigned short u16x8;
typedef __attribute__((ext_vector_type(4))) float f32x4;

// ws byte layout
#define ZP_OFF 0                 // 1 KB zero page (gload_lds OOB target)
#define F_OFF 1024
#define COORD_OFF 2048
#define SAMP_OFF 788480          // bf16 [b][4096][320] = 20,971,520 B
#define WT_OFF 21760000          // bf16 [tap][co][ci]  =  1,843,200 B

__device__ __forceinline__ u16 f2bf(float f) {
    union { float f; unsigned u; } v; v.f = f;
    unsigned r = v.u + 0x7fffu + ((v.u >> 16) & 1u);   // RNE
    return (u16)(r >> 16);
}
__device__ __forceinline__ float bf2f(u16 h) {
    union { unsigned u; float f; } v; v.u = ((unsigned)h) << 16;
    return v.f;
}
__device__ __forceinline__ void gl_lds16(const u16* g, u16* l) {
    __builtin_amdgcn_global_load_lds(
        (const __attribute__((address_space(1))) unsigned*)g,
        (__attribute__((address_space(3))) unsigned*)l, 16, 0, 0);
}

__device__ __forceinline__ void rodrigues3(float rv0, float rv1, float rv2, float* R) {
    float theta = sqrtf(rv0*rv0 + rv1*rv1 + rv2*rv2);
    float it = 1.0f / fmaxf(theta, 1e-12f);
    float r0 = rv0*it, r1 = rv1*it, r2 = rv2*it;
    float c = cosf(theta), s = sinf(theta), o = 1.0f - c;
    R[0]=c+o*r0*r0;    R[1]=o*r0*r1-s*r2; R[2]=o*r0*r2+s*r1;
    R[3]=o*r1*r0+s*r2; R[4]=c+o*r1*r1;    R[5]=o*r1*r2-s*r0;
    R[6]=o*r2*r0-s*r1; R[7]=o*r2*r1+s*r0; R[8]=c+o*r2*r2;
    if (theta < 1e-6f) { R[0]=1;R[1]=0;R[2]=0;R[3]=0;R[4]=1;R[5]=0;R[6]=0;R[7]=0;R[8]=1; }
}

__device__ __forceinline__ void inv3(const float* M, float* o) {
    float a=M[0],b=M[1],c=M[2],d=M[3],e=M[4],f=M[5],g=M[6],h=M[7],i=M[8];
    float A = e*i - f*h, B = f*g - d*i, C = d*h - e*g;
    float id = 1.0f / (a*A + b*B + c*C);
    o[0]=A*id;         o[1]=(c*h-b*i)*id; o[2]=(b*f-c*e)*id;
    o[3]=B*id;         o[4]=(a*i-c*g)*id; o[5]=(c*d-a*f)*id;
    o[6]=C*id;         o[7]=(b*g-a*h)*id; o[8]=(a*e-b*d)*id;
}

__global__ void k_fund(const float* __restrict__ Ks, const float* __restrict__ Kt,
                       const float* __restrict__ ps, const float* __restrict__ pt,
                       float* __restrict__ Fout, float* __restrict__ zp) {
    int t = threadIdx.x;
    for (int i = t; i < 256; i += 64) zp[i] = 0.0f;   // zero page (1 KB)
    int b = t;
    if (b >= BATCH) return;
    float Rs[9], Rt[9];
    rodrigues3(ps[b*6+0], ps[b*6+1], ps[b*6+2], Rs);
    rodrigues3(pt[b*6+0], pt[b*6+1], pt[b*6+2], Rt);
    float Rr[9];
    #pragma unroll
    for (int i = 0; i < 3; ++i)
      #pragma unroll
      for (int k = 0; k < 3; ++k)
        Rr[i*3+k] = Rs[i*3+0]*Rt[k*3+0] + Rs[i*3+1]*Rt[k*3+1] + Rs[i*3+2]*Rt[k*3+2];
    float tt0 = pt[b*6+3], tt1 = pt[b*6+4], tt2 = pt[b*6+5];
    float tr0 = ps[b*6+3] - (Rr[0]*tt0 + Rr[1]*tt1 + Rr[2]*tt2);
    float tr1 = ps[b*6+4] - (Rr[3]*tt0 + Rr[4]*tt1 + Rr[5]*tt2);
    float tr2 = ps[b*6+5] - (Rr[6]*tt0 + Rr[7]*tt1 + Rr[8]*tt2);
    float E[9];
    #pragma unroll
    for (int j = 0; j < 3; ++j) {
        E[0*3+j] = -tr2*Rr[1*3+j] + tr1*Rr[2*3+j];
        E[1*3+j] =  tr2*Rr[0*3+j] - tr0*Rr[2*3+j];
        E[2*3+j] = -tr1*Rr[0*3+j] + tr0*Rr[1*3+j];
    }
    float iKs[9], iKt[9];
    inv3(Ks + b*9, iKs);
    inv3(Kt + b*9, iKt);
    float T[9];
    #pragma unroll
    for (int i = 0; i < 3; ++i)
      #pragma unroll
      for (int k = 0; k < 3; ++k)
        T[i*3+k] = iKt[0*3+i]*E[0*3+k] + iKt[1*3+i]*E[1*3+k] + iKt[2*3+i]*E[2*3+k];
    #pragma unroll
    for (int i = 0; i < 3; ++i)
      #pragma unroll
      for (int l = 0; l < 3; ++l)
        Fout[b*9 + i*3 + l] = T[i*3+0]*iKs[0*3+l] + T[i*3+1]*iKs[1*3+l] + T[i*3+2]*iKs[2*3+l];
}

__global__ __launch_bounds__(256) void k_coords(const float* __restrict__ Fm,
                                                float* __restrict__ coords) {
    int b = blockIdx.y;
    int k = blockIdx.x * 256 + threadIdx.x;
    const float* F = Fm + b*9;
    float px = (float)(k & 63);
    float py = (float)(k >> 6);
    float a  = F[0]*px + F[3]*py + F[6];
    float bb = F[1]*px + F[4]*py + F[7];
    float c  = F[2]*px + F[5]*py + F[8];
    const float EPS = 1e-10f, W1 = 63.0f, H1 = 63.0f;
    float x1 = fminf(fmaxf(-c/(a+EPS), 0.0f), W1);
    float x2 = fminf(fmaxf(-(bb*H1+c)/(a+EPS), 0.0f), W1);
    float y1 = fminf(fmaxf(-c/(bb+EPS), 0.0f), H1);
    float y2 = fminf(fmaxf(-(a*W1+c)/(bb+EPS), 0.0f), H1);
    float* o = coords + ((size_t)b*HW + k)*6;
    o[0] = x1;                 o[1] = y1;
    o[2] = 0.5f*x1 + 0.5f*x2;  o[3] = 0.5f*y1 + 0.5f*y2;
    o[4] = x2;                 o[5] = y2;
}

// weights: OIHW fp32 -> [tap][co][ci] bf16
__global__ __launch_bounds__(256) void k_wprep(const float* __restrict__ wsrc,
                                               u16* __restrict__ wt) {
    int idx = blockIdx.x*256 + threadIdx.x;
    if (idx >= 9*CH*CH) return;
    int tap = idx / (CH*CH);
    int rem = idx - tap*(CH*CH);
    int co = rem / CH;
    int ci = rem - co*CH;
    wt[idx] = f2bf(wsrc[((size_t)co*CH + ci)*9 + tap]);
}

// bilinear sample, 8 channels/block, output channel-last bf16 [b][pix][320]
__global__ __launch_bounds__(256) void k_sample8(const float* __restrict__ x,
                                                 const float* __restrict__ coords,
                                                 u16* __restrict__ st) {
    __shared__ u16 pl[HW*8];   // 64 KB, [pix][8ch] bf16
    int cg = blockIdx.x, b = blockIdx.y;
    const float* xb = x + ((size_t)b*CH + cg*8)*HW;
    for (int i = threadIdx.x; i < HW; i += 256) {
        u16x8 v;
        #pragma unroll
        for (int c = 0; c < 8; ++c) v[c] = f2bf(xb[(size_t)c*HW + i]);
        *(u16x8*)(pl + i*8) = v;   // linear 16B/lane -> conflict-free
    }
    __syncthreads();
    const float* cb = coords + (size_t)b*HW*6;
    for (int k = threadIdx.x; k < HW; k += 256) {
        const float* cc = cb + (size_t)k*6;
        float acc[8];
        #pragma unroll
        for (int c = 0; c < 8; ++c) acc[c] = 0.f;
        #pragma unroll
        for (int s = 0; s < 3; ++s) {
            float sx = cc[s*2], sy = cc[s*2+1];
            float fx = floorf(sx), fy = floorf(sy);
            float wx = sx-fx, wy = sy-fy;
            int x0 = (int)fx, y0 = (int)fy;
            int x1 = min(x0+1,63), y1 = min(y0+1,63);
            u16x8 g00 = *(const u16x8*)(pl + (y0*64+x0)*8);
            u16x8 g10 = *(const u16x8*)(pl + (y0*64+x1)*8);
            u16x8 g01 = *(const u16x8*)(pl + (y1*64+x0)*8);
            u16x8 g11 = *(const u16x8*)(pl + (y1*64+x1)*8);
            float w00=(1.f-wx)*(1.f-wy), w10=wx*(1.f-wy), w01=(1.f-wx)*wy, w11=wx*wy;
            #pragma unroll
            for (int c = 0; c < 8; ++c)
                acc[c] += w00*bf2f(g00[c]) + w10*bf2f(g10[c])
                        + w01*bf2f(g01[c]) + w11*bf2f(g11[c]);
        }
        u16x8 o;
        #pragma unroll
        for (int c = 0; c < 8; ++c) o[c] = f2bf(acc[c]*(1.f/3.f));
        *(u16x8*)(st + ((size_t)b*HW + k)*CH + cg*8) = o;
    }
}

// implicit-GEMM conv: block = 64co x 2 rows(128 pix), 2 waves, wave = 64co x 64pix.
// LDS: 4 halo rows x 66 cols x 32ci bf16, granule-swizzled (slot = ks ^ ((col>>1)&3)).
// Staged by global_load_lds w16 with the swizzle applied on the global source side.
// 18 staging instructions x 1024 B = 18432 B LDS (granules >=1056 are slack; never read).
__global__ __launch_bounds__(128) void k_conv(const u16* __restrict__ st,
                                              const u16* __restrict__ wt,
                                              const float* __restrict__ bias,
                                              const float* __restrict__ zp,
                                              float* __restrict__ out) {
    __shared__ u16 lds[9216];   // 18432 B  (was 8704 -> OOB async writes; round-2 crash)
    int rowblk = blockIdx.x;    // 0..31
    int coblk  = blockIdx.y;    // 0..4
    int b      = blockIdx.z;
    int y0 = rowblk*2;
    int co0 = coblk*64;
    int lane = threadIdx.x & 63;
    int w = threadIdx.x >> 6;
    int l15 = lane & 15, l4 = lane >> 4;

    // per-lane staging source addresses (granule-swizzled global side, linear LDS)
    const u16* ga[9];
    #pragma unroll
    for (int jj = 0; jj < 9; ++jj) {
        int j = 2*jj + w;
        int g = j*64 + lane;
        int row_l = g/264;                 // 264 granules (4224 B) per halo row
        int rem = g - row_l*264;
        int col = rem >> 2;
        int slot = rem & 3;
        int ks = slot ^ ((col>>1)&3);      // involution swizzle
        int yy = y0 - 1 + row_l;
        int xx = col - 1;
        bool oob = (g >= 1056) | (yy < 0) | (yy > 63) | (xx < 0) | (xx > 63);
        int yc = min(max(yy,0),63), xc = min(max(xx,0),63);
        const u16* p = st + (((size_t)b*HW) + yc*64 + xc)*CH + ks*8;
        ga[jj] = oob ? (const u16*)zp : p;
    }

    f32x4 acc[4][4];
    #pragma unroll
    for (int mr = 0; mr < 4; ++mr)
        #pragma unroll
        for (int nf = 0; nf < 4; ++nf) acc[mr][nf] = (f32x4){0.f,0.f,0.f,0.f};

    for (int c = 0; c < 10; ++c) {          // ci chunks of 32
        int ci0 = c*32;
        __syncthreads();                    // prev compute done
        #pragma unroll
        for (int jj = 0; jj < 9; ++jj) {
            int j = 2*jj + w;
            if (jj < 8 || w == 0) {
                gl_lds16(ga[jj], (u16*)((char*)lds + j*1024));
            }
        }
        #pragma unroll
        for (int jj = 0; jj < 9; ++jj) ga[jj] += 32;   // next 32 channels (64 B)
        __syncthreads();                    // drains vmcnt before compute

        #pragma unroll
        for (int ky = 0; ky < 3; ++ky) {
            int rowbase = (w + ky) * 4224;
            #pragma unroll
            for (int kx = 0; kx < 3; ++kx) {
                int tap = ky*3 + kx;
                bf16x8 a[4];
                #pragma unroll
                for (int mr = 0; mr < 4; ++mr) {
                    int co = co0 + mr*16 + l15;
                    a[mr] = *(const bf16x8*)(wt + ((size_t)(tap*CH + co))*CH + ci0 + l4*8);
                }
                bf16x8 bb[4];
                #pragma unroll
                for (int nf = 0; nf < 4; ++nf) {
                    int col = nf*16 + l15 + kx;
                    int boff = rowbase + col*64 + ((l4 ^ ((col>>1)&3))<<4);
                    bb[nf] = *(const bf16x8*)((const char*)lds + boff);
                }
                #pragma unroll
                for (int mr = 0; mr < 4; ++mr)
                    #pragma unroll
                    for (int nf = 0; nf < 4; ++nf)
                        acc[mr][nf] = __builtin_amdgcn_mfma_f32_16x16x32_bf16(
                            a[mr], bb[nf], acc[mr][nf], 0, 0, 0);
            }
        }
    }

    int y = y0 + w;
    #pragma unroll
    for (int mr = 0; mr < 4; ++mr) {
        #pragma unroll
        for (int r = 0; r < 4; ++r) {
            int co = co0 + mr*16 + l4*4 + r;
            float bv = bias[co];
            float* ob = out + ((size_t)(b*CH + co))*HW + y*64;
            #pragma unroll
            for (int nf = 0; nf < 4; ++nf) {
                int xx = nf*16 + l15;
                ob[xx] = fmaxf(acc[mr][nf][r] + bv, 0.f);
            }
        }
    }
}

extern "C" void kernel_launch(void* const* d_in, const int* in_sizes, int n_in,
                              void* d_out, int out_size, void* d_ws, size_t ws_size,
                              hipStream_t stream) {
    const float* x  = (const float*)d_in[0];
    const float* Ks = (const float*)d_in[1];
    const float* Kt = (const float*)d_in[2];
    const float* ps = (const float*)d_in[3];
    const float* pt = (const float*)d_in[4];
    const float* cw = (const float*)d_in[5];
    const float* cb = (const float*)d_in[6];
    float* out = (float*)d_out;
    char* ws = (char*)d_ws;
    float* zp     = (float*)(ws + ZP_OFF);
    float* F      = (float*)(ws + F_OFF);
    float* coords = (float*)(ws + COORD_OFF);
    u16*   st     = (u16*)(ws + SAMP_OFF);
    u16*   wt     = (u16*)(ws + WT_OFF);

    k_fund<<<1, 64, 0, stream>>>(Ks, Kt, ps, pt, F, zp);
    k_wprep<<<(9*CH*CH + 255)/256, 256, 0, stream>>>(cw, wt);
    k_coords<<<dim3(HW/256, BATCH), 256, 0, stream>>>(F, coords);
    k_sample8<<<dim3(CH/8, BATCH), 256, 0, stream>>>(x, coords, st);
    k_conv<<<dim3(32, 5, BATCH), 128, 0, stream>>>(st, wt, cb, zp, out);
}

// Round 6
// 120.636 us; speedup vs baseline: 34.2113x; 1.4916x over previous
//
#include <hip/hip_runtime.h>
#include <math.h>

#define BATCH 8
#define CH 320
#define HW 4096

typedef unsigned short u16;
typedef __attribute__((ext_vector_type(8))) short bf16x8;
typedef __attribute__((ext_vector_type(8))) unsigned short u16x8;
typedef __attribute__((ext_vector_type(4))) float f32x4;

// ws byte layout
#define ZP_OFF 0                 // 1 KB zero page (gload_lds OOB target)
#define F_OFF 1024
#define COORD_OFF 2048
#define SAMP_OFF 788480          // bf16 [b][4096][320] = 20,971,520 B
#define WT_OFF 21760000          // bf16 [tap][chunk][co][32] = 1,843,200 B

__device__ __forceinline__ u16 f2bf(float f) {
    union { float f; unsigned u; } v; v.f = f;
    unsigned r = v.u + 0x7fffu + ((v.u >> 16) & 1u);   // RNE
    return (u16)(r >> 16);
}
__device__ __forceinline__ float bf2f(u16 h) {
    union { unsigned u; float f; } v; v.u = ((unsigned)h) << 16;
    return v.f;
}
__device__ __forceinline__ void gl_lds16(const u16* g, u16* l) {
    __builtin_amdgcn_global_load_lds(
        (const __attribute__((address_space(1))) unsigned*)g,
        (__attribute__((address_space(3))) unsigned*)l, 16, 0, 0);
}

__device__ __forceinline__ void rodrigues3(float rv0, float rv1, float rv2, float* R) {
    float theta = sqrtf(rv0*rv0 + rv1*rv1 + rv2*rv2);
    float it = 1.0f / fmaxf(theta, 1e-12f);
    float r0 = rv0*it, r1 = rv1*it, r2 = rv2*it;
    float c = cosf(theta), s = sinf(theta), o = 1.0f - c;
    R[0]=c+o*r0*r0;    R[1]=o*r0*r1-s*r2; R[2]=o*r0*r2+s*r1;
    R[3]=o*r1*r0+s*r2; R[4]=c+o*r1*r1;    R[5]=o*r1*r2-s*r0;
    R[6]=o*r2*r0-s*r1; R[7]=o*r2*r1+s*r0; R[8]=c+o*r2*r2;
    if (theta < 1e-6f) { R[0]=1;R[1]=0;R[2]=0;R[3]=0;R[4]=1;R[5]=0;R[6]=0;R[7]=0;R[8]=1; }
}

__device__ __forceinline__ void inv3(const float* M, float* o) {
    float a=M[0],b=M[1],c=M[2],d=M[3],e=M[4],f=M[5],g=M[6],h=M[7],i=M[8];
    float A = e*i - f*h, B = f*g - d*i, C = d*h - e*g;
    float id = 1.0f / (a*A + b*B + c*C);
    o[0]=A*id;         o[1]=(c*h-b*i)*id; o[2]=(b*f-c*e)*id;
    o[3]=B*id;         o[4]=(a*i-c*g)*id; o[5]=(c*d-a*f)*id;
    o[6]=C*id;         o[7]=(b*g-a*h)*id; o[8]=(a*e-b*d)*id;
}

__global__ void k_fund(const float* __restrict__ Ks, const float* __restrict__ Kt,
                       const float* __restrict__ ps, const float* __restrict__ pt,
                       float* __restrict__ Fout, float* __restrict__ zp) {
    int t = threadIdx.x;
    for (int i = t; i < 256; i += 64) zp[i] = 0.0f;   // zero page (1 KB)
    int b = t;
    if (b >= BATCH) return;
    float Rs[9], Rt[9];
    rodrigues3(ps[b*6+0], ps[b*6+1], ps[b*6+2], Rs);
    rodrigues3(pt[b*6+0], pt[b*6+1], pt[b*6+2], Rt);
    float Rr[9];
    #pragma unroll
    for (int i = 0; i < 3; ++i)
      #pragma unroll
      for (int k = 0; k < 3; ++k)
        Rr[i*3+k] = Rs[i*3+0]*Rt[k*3+0] + Rs[i*3+1]*Rt[k*3+1] + Rs[i*3+2]*Rt[k*3+2];
    float tt0 = pt[b*6+3], tt1 = pt[b*6+4], tt2 = pt[b*6+5];
    float tr0 = ps[b*6+3] - (Rr[0]*tt0 + Rr[1]*tt1 + Rr[2]*tt2);
    float tr1 = ps[b*6+4] - (Rr[3]*tt0 + Rr[4]*tt1 + Rr[5]*tt2);
    float tr2 = ps[b*6+5] - (Rr[6]*tt0 + Rr[7]*tt1 + Rr[8]*tt2);
    float E[9];
    #pragma unroll
    for (int j = 0; j < 3; ++j) {
        E[0*3+j] = -tr2*Rr[1*3+j] + tr1*Rr[2*3+j];
        E[1*3+j] =  tr2*Rr[0*3+j] - tr0*Rr[2*3+j];
        E[2*3+j] = -tr1*Rr[0*3+j] + tr0*Rr[1*3+j];
    }
    float iKs[9], iKt[9];
    inv3(Ks + b*9, iKs);
    inv3(Kt + b*9, iKt);
    float T[9];
    #pragma unroll
    for (int i = 0; i < 3; ++i)
      #pragma unroll
      for (int k = 0; k < 3; ++k)
        T[i*3+k] = iKt[0*3+i]*E[0*3+k] + iKt[1*3+i]*E[1*3+k] + iKt[2*3+i]*E[2*3+k];
    #pragma unroll
    for (int i = 0; i < 3; ++i)
      #pragma unroll
      for (int l = 0; l < 3; ++l)
        Fout[b*9 + i*3 + l] = T[i*3+0]*iKs[0*3+l] + T[i*3+1]*iKs[1*3+l] + T[i*3+2]*iKs[2*3+l];
}

__global__ __launch_bounds__(256) void k_coords(const float* __restrict__ Fm,
                                                float* __restrict__ coords) {
    int b = blockIdx.y;
    int k = blockIdx.x * 256 + threadIdx.x;
    const float* F = Fm + b*9;
    float px = (float)(k & 63);
    float py = (float)(k >> 6);
    float a  = F[0]*px + F[3]*py + F[6];
    float bb = F[1]*px + F[4]*py + F[7];
    float c  = F[2]*px + F[5]*py + F[8];
    const float EPS = 1e-10f, W1 = 63.0f, H1 = 63.0f;
    float x1 = fminf(fmaxf(-c/(a+EPS), 0.0f), W1);
    float x2 = fminf(fmaxf(-(bb*H1+c)/(a+EPS), 0.0f), W1);
    float y1 = fminf(fmaxf(-c/(bb+EPS), 0.0f), H1);
    float y2 = fminf(fmaxf(-(a*W1+c)/(bb+EPS), 0.0f), H1);
    float* o = coords + ((size_t)b*HW + k)*6;
    o[0] = x1;                 o[1] = y1;
    o[2] = 0.5f*x1 + 0.5f*x2;  o[3] = 0.5f*y1 + 0.5f*y2;
    o[4] = x2;                 o[5] = y2;
}

// weights: OIHW fp32 -> [tap][ci_chunk][co][ci_in_chunk] bf16 (coalesced A-frag loads)
__global__ __launch_bounds__(256) void k_wprep(const float* __restrict__ wsrc,
                                               u16* __restrict__ wt) {
    int idx = blockIdx.x*256 + threadIdx.x;
    if (idx >= 9*CH*CH) return;
    int cl = idx & 31;
    int t  = idx >> 5;
    int co = t % CH;
    int t2 = t / CH;
    int ch = t2 % 10;
    int tap = t2 / 10;
    int ci = ch*32 + cl;
    wt[idx] = f2bf(wsrc[((size_t)co*CH + ci)*9 + tap]);
}

// bilinear sample, 8 channels/block, output channel-last bf16 [b][pix][320]
__global__ __launch_bounds__(256) void k_sample8(const float* __restrict__ x,
                                                 const float* __restrict__ coords,
                                                 u16* __restrict__ st) {
    __shared__ u16 pl[HW*8];   // 64 KB, [pix][8ch] bf16
    int cg = blockIdx.x, b = blockIdx.y;
    const float* xb = x + ((size_t)b*CH + cg*8)*HW;
    for (int i = threadIdx.x; i < HW; i += 256) {
        u16x8 v;
        #pragma unroll
        for (int c = 0; c < 8; ++c) v[c] = f2bf(xb[(size_t)c*HW + i]);
        *(u16x8*)(pl + i*8) = v;
    }
    __syncthreads();
    const float* cb = coords + (size_t)b*HW*6;
    for (int k = threadIdx.x; k < HW; k += 256) {
        const float* cc = cb + (size_t)k*6;
        float acc[8];
        #pragma unroll
        for (int c = 0; c < 8; ++c) acc[c] = 0.f;
        #pragma unroll
        for (int s = 0; s < 3; ++s) {
            float sx = cc[s*2], sy = cc[s*2+1];
            float fx = floorf(sx), fy = floorf(sy);
            float wx = sx-fx, wy = sy-fy;
            int x0 = (int)fx, y0 = (int)fy;
            int x1 = min(x0+1,63), y1 = min(y0+1,63);
            u16x8 g00 = *(const u16x8*)(pl + (y0*64+x0)*8);
            u16x8 g10 = *(const u16x8*)(pl + (y0*64+x1)*8);
            u16x8 g01 = *(const u16x8*)(pl + (y1*64+x0)*8);
            u16x8 g11 = *(const u16x8*)(pl + (y1*64+x1)*8);
            float w00=(1.f-wx)*(1.f-wy), w10=wx*(1.f-wy), w01=(1.f-wx)*wy, w11=wx*wy;
            #pragma unroll
            for (int c = 0; c < 8; ++c)
                acc[c] += w00*bf2f(g00[c]) + w10*bf2f(g10[c])
                        + w01*bf2f(g01[c]) + w11*bf2f(g11[c]);
        }
        u16x8 o;
        #pragma unroll
        for (int c = 0; c < 8; ++c) o[c] = f2bf(acc[c]*(1.f/3.f));
        *(u16x8*)(st + ((size_t)b*HW + k)*CH + cg*8) = o;
    }
}

// implicit-GEMM conv. Block = 512 thr (8 waves) = 320co x 128pix (2 rows).
// Wave (w>>1) owns 80-co group, (w&1) owns output row. 1 block/CU (grid=256).
// Input tile (4 halo rows x 66 cols x 32ci, granule-swizzled) double-buffered in LDS,
// prefetched one chunk ahead via global_load_lds; weights [tap][chunk][co][32] give
// fully-coalesced 1KB A-frag loads from L2.
// launch_bounds (512,1): 256-VGPR budget. (512,2) would cap at 128 VGPR -> spills;
// grid is 1 block/CU anyway so the tighter bound bought nothing.
__global__ __launch_bounds__(512, 1) void k_conv(const u16* __restrict__ st,
                                                 const u16* __restrict__ wt,
                                                 const float* __restrict__ bias,
                                                 const float* __restrict__ zp,
                                                 float* __restrict__ out) {
    __shared__ u16 lds[2*8704];   // 2 x 17408 B double buffer
    int rowblk = blockIdx.x;      // 0..31
    int b      = blockIdx.y;
    int y0 = rowblk*2;
    int lane = threadIdx.x & 63;
    int w = threadIdx.x >> 6;     // 0..7
    int wrow = w & 1;             // output row within the pair
    int co0w = (w >> 1) * 80;     // 80-co group
    int l15 = lane & 15, l4 = lane >> 4;

    // staging: 1056 granules over 17 slot-instructions; wave w takes slots {w, 8+w},
    // wave 0 additionally slot 16 (granules >=1056 are OOB -> zero page).
    const u16* ga[3];
    int js[3];
    #pragma unroll
    for (int s = 0; s < 3; ++s) {
        int j = (s < 2) ? (s*8 + w) : 16;
        js[s] = j;
        int g = j*64 + lane;
        int row_l = g/264;                 // 264 granules (4224 B) per halo row
        int rem = g - row_l*264;
        int col = rem >> 2;
        int slot = rem & 3;
        int ks = slot ^ ((col>>1)&3);      // involution swizzle
        int yy = y0 - 1 + row_l;
        int xx = col - 1;
        bool oob = (g >= 1056) | (yy < 0) | (yy > 63) | (xx < 0) | (xx > 63);
        int yc = min(max(yy,0),63), xc = min(max(xx,0),63);
        const u16* p = st + (((size_t)b*HW) + yc*64 + xc)*CH + ks*8;
        ga[s] = oob ? (const u16*)zp : p;
    }
    int nslot = (w == 0) ? 3 : 2;

    f32x4 acc[5][4];
    #pragma unroll
    for (int mr = 0; mr < 5; ++mr)
        #pragma unroll
        for (int nf = 0; nf < 4; ++nf) acc[mr][nf] = (f32x4){0.f,0.f,0.f,0.f};

    // prologue: stage chunk 0 into buffer 0
    #pragma unroll
    for (int s = 0; s < 3; ++s)
        if (s < nslot) gl_lds16(ga[s], (u16*)((char*)lds + js[s]*1024));
    #pragma unroll
    for (int s = 0; s < 3; ++s) ga[s] += 32;    // advance 32 ci (64 B)
    __syncthreads();

    for (int c = 0; c < 10; ++c) {
        int cur = c & 1;
        // prefetch next chunk into the other buffer (overlaps with compute below)
        if (c < 9) {
            #pragma unroll
            for (int s = 0; s < 3; ++s)
                if (s < nslot) gl_lds16(ga[s], (u16*)((char*)lds + (cur^1)*17408 + js[s]*1024));
            #pragma unroll
            for (int s = 0; s < 3; ++s) ga[s] += 32;
        }
        const char* buf = (const char*)lds + cur*17408;
        #pragma unroll
        for (int ky = 0; ky < 3; ++ky) {
            int rowbase = (wrow + ky) * 4224;
            #pragma unroll
            for (int kx = 0; kx < 3; ++kx) {
                int tap = ky*3 + kx;
                const u16* wbase = wt + ((size_t)(tap*10 + c)*CH)*32;
                bf16x8 a[5];
                #pragma unroll
                for (int mr = 0; mr < 5; ++mr)
                    a[mr] = *(const bf16x8*)(wbase + (co0w + mr*16 + l15)*32 + l4*8);
                bf16x8 bb[4];
                #pragma unroll
                for (int nf = 0; nf < 4; ++nf) {
                    int col = nf*16 + l15 + kx;
                    int boff = rowbase + col*64 + ((l4 ^ ((col>>1)&3))<<4);
                    bb[nf] = *(const bf16x8*)(buf + boff);
                }
                #pragma unroll
                for (int mr = 0; mr < 5; ++mr)
                    #pragma unroll
                    for (int nf = 0; nf < 4; ++nf)
                        acc[mr][nf] = __builtin_amdgcn_mfma_f32_16x16x32_bf16(
                            a[mr], bb[nf], acc[mr][nf], 0, 0, 0);
            }
        }
        __syncthreads();   // drains vmcnt (prefetch done) + separates buffers
    }

    int y = y0 + wrow;
    #pragma unroll
    for (int mr = 0; mr < 5; ++mr) {
        #pragma unroll
        for (int r = 0; r < 4; ++r) {
            int co = co0w + mr*16 + l4*4 + r;
            float bv = bias[co];
            float* ob = out + ((size_t)(b*CH + co))*HW + y*64;
            #pragma unroll
            for (int nf = 0; nf < 4; ++nf) {
                int xx = nf*16 + l15;
                ob[xx] = fmaxf(acc[mr][nf][r] + bv, 0.f);
            }
        }
    }
}

extern "C" void kernel_launch(void* const* d_in, const int* in_sizes, int n_in,
                              void* d_out, int out_size, void* d_ws, size_t ws_size,
                              hipStream_t stream) {
    const float* x  = (const float*)d_in[0];
    const float* Ks = (const float*)d_in[1];
    const float* Kt = (const float*)d_in[2];
    const float* ps = (const float*)d_in[3];
    const float* pt = (const float*)d_in[4];
    const float* cw = (const float*)d_in[5];
    const float* cb = (const float*)d_in[6];
    float* out = (float*)d_out;
    char* ws = (char*)d_ws;
    float* zp     = (float*)(ws + ZP_OFF);
    float* F      = (float*)(ws + F_OFF);
    float* coords = (float*)(ws + COORD_OFF);
    u16*   st     = (u16*)(ws + SAMP_OFF);
    u16*   wt     = (u16*)(ws + WT_OFF);

    k_fund<<<1, 64, 0, stream>>>(Ks, Kt, ps, pt, F, zp);
    k_wprep<<<(9*CH*CH + 255)/256, 256, 0, stream>>>(cw, wt);
    k_coords<<<dim3(HW/256, BATCH), 256, 0, stream>>>(F, coords);
    k_sample8<<<dim3(CH/8, BATCH), 256, 0, stream>>>(x, coords, st);
    k_conv<<<dim3(32, BATCH), 512, 0, stream>>>(st, wt, cb, zp, out);
}

// Round 8
// 116.653 us; speedup vs baseline: 35.3792x; 1.0341x over previous
//
#include <hip/hip_runtime.h>
#include <math.h>

#define BATCH 8
#define CH 320
#define HW 4096

typedef unsigned short u16;
typedef __attribute__((ext_vector_type(8))) short bf16x8;
typedef __attribute__((ext_vector_type(8))) unsigned short u16x8;
typedef __attribute__((ext_vector_type(4))) float f32x4;
typedef __attribute__((ext_vector_type(4))) float float4v;

// ws byte layout
#define ZP_OFF 0                 // 1 KB zero page (gload_lds OOB target)
#define SAMP_OFF 788480          // bf16 [b][4096][320] = 20,971,520 B
#define WT_OFF 21760000          // bf16 [chunk][tap][co][32] = 1,843,200 B

__device__ __forceinline__ u16 f2bf(float f) {
    union { float f; unsigned u; } v; v.f = f;
    unsigned r = v.u + 0x7fffu + ((v.u >> 16) & 1u);   // RNE
    return (u16)(r >> 16);
}
__device__ __forceinline__ float bf2f(u16 h) {
    union { unsigned u; float f; } v; v.u = ((unsigned)h) << 16;
    return v.f;
}
__device__ __forceinline__ void gl_lds16(const u16* g, u16* l) {
    __builtin_amdgcn_global_load_lds(
        (const __attribute__((address_space(1))) unsigned*)g,
        (__attribute__((address_space(3))) unsigned*)l, 16, 0, 0);
}

__device__ __forceinline__ void rodrigues3(float rv0, float rv1, float rv2, float* R) {
    float theta = sqrtf(rv0*rv0 + rv1*rv1 + rv2*rv2);
    float it = 1.0f / fmaxf(theta, 1e-12f);
    float r0 = rv0*it, r1 = rv1*it, r2 = rv2*it;
    float c = cosf(theta), s = sinf(theta), o = 1.0f - c;
    R[0]=c+o*r0*r0;    R[1]=o*r0*r1-s*r2; R[2]=o*r0*r2+s*r1;
    R[3]=o*r1*r0+s*r2; R[4]=c+o*r1*r1;    R[5]=o*r1*r2-s*r0;
    R[6]=o*r2*r0-s*r1; R[7]=o*r2*r1+s*r0; R[8]=c+o*r2*r2;
    if (theta < 1e-6f) { R[0]=1;R[1]=0;R[2]=0;R[3]=0;R[4]=1;R[5]=0;R[6]=0;R[7]=0;R[8]=1; }
}

__device__ __forceinline__ void inv3(const float* M, float* o) {
    float a=M[0],b=M[1],c=M[2],d=M[3],e=M[4],f=M[5],g=M[6],h=M[7],i=M[8];
    float A = e*i - f*h, B = f*g - d*i, C = d*h - e*g;
    float id = 1.0f / (a*A + b*B + c*C);
    o[0]=A*id;         o[1]=(c*h-b*i)*id; o[2]=(b*f-c*e)*id;
    o[3]=B*id;         o[4]=(a*i-c*g)*id; o[5]=(c*d-a*f)*id;
    o[6]=C*id;         o[7]=(b*g-a*h)*id; o[8]=(a*e-b*d)*id;
}

// fundamental matrix for batch b (computed redundantly per thread; ~300 VALU ops)
__device__ void compute_F(const float* Ks, const float* Kt, const float* ps,
                          const float* pt, int b, float* Fm) {
    float Rs[9], Rt[9];
    rodrigues3(ps[b*6+0], ps[b*6+1], ps[b*6+2], Rs);
    rodrigues3(pt[b*6+0], pt[b*6+1], pt[b*6+2], Rt);
    float Rr[9];
    #pragma unroll
    for (int i = 0; i < 3; ++i)
      #pragma unroll
      for (int k = 0; k < 3; ++k)
        Rr[i*3+k] = Rs[i*3+0]*Rt[k*3+0] + Rs[i*3+1]*Rt[k*3+1] + Rs[i*3+2]*Rt[k*3+2];
    float tt0 = pt[b*6+3], tt1 = pt[b*6+4], tt2 = pt[b*6+5];
    float tr0 = ps[b*6+3] - (Rr[0]*tt0 + Rr[1]*tt1 + Rr[2]*tt2);
    float tr1 = ps[b*6+4] - (Rr[3]*tt0 + Rr[4]*tt1 + Rr[5]*tt2);
    float tr2 = ps[b*6+5] - (Rr[6]*tt0 + Rr[7]*tt1 + Rr[8]*tt2);
    float E[9];
    #pragma unroll
    for (int j = 0; j < 3; ++j) {
        E[0*3+j] = -tr2*Rr[1*3+j] + tr1*Rr[2*3+j];
        E[1*3+j] =  tr2*Rr[0*3+j] - tr0*Rr[2*3+j];
        E[2*3+j] = -tr1*Rr[0*3+j] + tr0*Rr[1*3+j];
    }
    float iKs[9], iKt[9];
    inv3(Ks + b*9, iKs);
    inv3(Kt + b*9, iKt);
    float T[9];
    #pragma unroll
    for (int i = 0; i < 3; ++i)
      #pragma unroll
      for (int k = 0; k < 3; ++k)
        T[i*3+k] = iKt[0*3+i]*E[0*3+k] + iKt[1*3+i]*E[1*3+k] + iKt[2*3+i]*E[2*3+k];
    #pragma unroll
    for (int i = 0; i < 3; ++i)
      #pragma unroll
      for (int l = 0; l < 3; ++l)
        Fm[i*3 + l] = T[i*3+0]*iKs[0*3+l] + T[i*3+1]*iKs[1*3+l] + T[i*3+2]*iKs[2*3+l];
}

// weights: OIHW fp32 -> [ci_chunk][tap][co][ci_in_chunk] bf16 (linear A-stream in conv)
// + zero-page init
__global__ __launch_bounds__(256) void k_wprep(const float* __restrict__ wsrc,
                                               u16* __restrict__ wt,
                                               float* __restrict__ zp) {
    int idx = blockIdx.x*256 + threadIdx.x;
    if (blockIdx.x == 0) zp[threadIdx.x] = 0.0f;   // 1 KB zero page
    if (idx >= 9*CH*CH) return;
    int cl = idx & 31;
    int r  = idx >> 5;
    int co = r % CH;
    int q  = r / CH;
    int t  = q % 9;       // tap
    int c  = q / 9;       // ci chunk
    int ci = c*32 + cl;
    wt[idx] = f2bf(wsrc[((size_t)co*CH + ci)*9 + t]);
}

// fused: fundamental matrix + epipolar line + bilinear sample (3 pts, mean).
// 8 channels/block; output channel-last bf16 [b][pix][320]
__global__ __launch_bounds__(256) void k_sample8(const float* __restrict__ x,
                                                 const float* __restrict__ Ks,
                                                 const float* __restrict__ Kt,
                                                 const float* __restrict__ ps,
                                                 const float* __restrict__ pt,
                                                 u16* __restrict__ st) {
    __shared__ u16 pl[HW*8];   // 64 KB, [pix][8ch] bf16
    int cg = blockIdx.x, b = blockIdx.y;
    int tid = threadIdx.x;
    const float* xb = x + ((size_t)b*CH + cg*8)*HW;
    const float4v* xb4 = (const float4v*)xb;
    #pragma unroll
    for (int it = 0; it < 4; ++it) {
        int i0 = (it*256 + tid)*4;
        float4v v[8];
        #pragma unroll
        for (int c = 0; c < 8; ++c) v[c] = xb4[c*(HW/4) + it*256 + tid];
        #pragma unroll
        for (int j = 0; j < 4; ++j) {
            u16x8 o;
            #pragma unroll
            for (int c = 0; c < 8; ++c) o[c] = f2bf(v[c][j]);
            *(u16x8*)(pl + (i0 + j)*8) = o;
        }
    }
    float Fm[9];
    compute_F(Ks, Kt, ps, pt, b, Fm);
    __syncthreads();
    const float EPS = 1e-10f, W1 = 63.0f, H1 = 63.0f;
    for (int k = tid; k < HW; k += 256) {
        float px = (float)(k & 63);
        float py = (float)(k >> 6);
        float a  = Fm[0]*px + Fm[3]*py + Fm[6];
        float bb = Fm[1]*px + Fm[4]*py + Fm[7];
        float c  = Fm[2]*px + Fm[5]*py + Fm[8];
        float x1 = fminf(fmaxf(-c/(a+EPS), 0.0f), W1);
        float x2 = fminf(fmaxf(-(bb*H1+c)/(a+EPS), 0.0f), W1);
        float y1 = fminf(fmaxf(-c/(bb+EPS), 0.0f), H1);
        float y2 = fminf(fmaxf(-(a*W1+c)/(bb+EPS), 0.0f), H1);
        float sxs[3], sys[3];
        sxs[0] = x1; sys[0] = y1;
        sxs[1] = 0.5f*(x1+x2); sys[1] = 0.5f*(y1+y2);
        sxs[2] = x2; sys[2] = y2;
        float acc[8];
        #pragma unroll
        for (int c2 = 0; c2 < 8; ++c2) acc[c2] = 0.f;
        #pragma unroll
        for (int s = 0; s < 3; ++s) {
            float sx = sxs[s], sy = sys[s];
            float fx = floorf(sx), fy = floorf(sy);
            float wx = sx-fx, wy = sy-fy;
            int x0 = (int)fx, y0 = (int)fy;
            int x1i = min(x0+1,63), y1i = min(y0+1,63);
            u16x8 g00 = *(const u16x8*)(pl + (y0*64+x0)*8);
            u16x8 g10 = *(const u16x8*)(pl + (y0*64+x1i)*8);
            u16x8 g01 = *(const u16x8*)(pl + (y1i*64+x0)*8);
            u16x8 g11 = *(const u16x8*)(pl + (y1i*64+x1i)*8);
            float w00=(1.f-wx)*(1.f-wy), w10=wx*(1.f-wy), w01=(1.f-wx)*wy, w11=wx*wy;
            #pragma unroll
            for (int c2 = 0; c2 < 8; ++c2)
                acc[c2] += w00*bf2f(g00[c2]) + w10*bf2f(g10[c2])
                         + w01*bf2f(g01[c2]) + w11*bf2f(g11[c2]);
        }
        u16x8 o;
        #pragma unroll
        for (int c2 = 0; c2 < 8; ++c2) o[c2] = f2bf(acc[c2]*(1.f/3.f));
        *(u16x8*)(st + ((size_t)b*HW + k)*CH + cg*8) = o;
    }
}

// implicit-GEMM conv. Block = 512 thr (8 waves) = 320co x 128pix (2 rows).
// Wave (w>>1) owns 80-co group, (w&1) owns output row. Grid 256 = 1 block/CU.
// Input tile (4 halo rows x 66 cols x 32ci, granule-swizzled) double-buffered in LDS,
// prefetched one chunk ahead via global_load_lds. Weights [chunk][tap][co][32]:
// linear 1KB/wave A-stream from L2, software-pipelined one tap ahead (aN/bbN)
// so L2/LDS latency hides under the 20-MFMA cluster.
__global__ __launch_bounds__(512, 1) void k_conv(const u16* __restrict__ st,
                                                 const u16* __restrict__ wt,
                                                 const float* __restrict__ bias,
                                                 const float* __restrict__ zp,
                                                 float* __restrict__ out) {
    __shared__ u16 lds[2*8704];   // 2 x 17408 B double buffer
    int rowblk = blockIdx.x;      // 0..31
    int b      = blockIdx.y;
    int y0 = rowblk*2;
    int lane = threadIdx.x & 63;
    int w = threadIdx.x >> 6;     // 0..7
    int wrow = w & 1;
    int co0w = (w >> 1) * 80;
    int l15 = lane & 15, l4 = lane >> 4;

    // staging: 1056 granules over 17 slot-instructions; wave w takes slots {w, 8+w},
    // wave 0 additionally slot 16 (granules >=1056 OOB -> zero page).
    const u16* ga[3];
    int js[3];
    #pragma unroll
    for (int s = 0; s < 3; ++s) {
        int j = (s < 2) ? (s*8 + w) : 16;
        js[s] = j;
        int g = j*64 + lane;
        int row_l = g/264;                 // 264 granules (4224 B) per halo row
        int rem = g - row_l*264;
        int col = rem >> 2;
        int slot = rem & 3;
        int ks = slot ^ ((col>>1)&3);      // involution swizzle
        int yy = y0 - 1 + row_l;
        int xx = col - 1;
        bool oob = (g >= 1056) | (yy < 0) | (yy > 63) | (xx < 0) | (xx > 63);
        int yc = min(max(yy,0),63), xc = min(max(xx,0),63);
        const u16* p = st + (((size_t)b*HW) + yc*64 + xc)*CH + ks*8;
        ga[s] = oob ? (const u16*)zp : p;
    }
    int nslot = (w == 0) ? 3 : 2;

    // per-thread weight base; address for (c,t,mr) = wthr + (c*9+t)*CH*32 + mr*512
    const u16* wthr = wt + (size_t)(co0w + l15)*32 + l4*8;

    f32x4 acc[5][4];
    #pragma unroll
    for (int mr = 0; mr < 5; ++mr)
        #pragma unroll
        for (int nf = 0; nf < 4; ++nf) acc[mr][nf] = (f32x4){0.f,0.f,0.f,0.f};

    // prologue: stage chunk 0 into buffer 0; load A(c=0,t=0)
    #pragma unroll
    for (int s = 0; s < 3; ++s)
        if (s < nslot) gl_lds16(ga[s], (u16*)((char*)lds + js[s]*1024));
    #pragma unroll
    for (int s = 0; s < 3; ++s) ga[s] += 32;

    bf16x8 aC[5], aN[5], bbC[4], bbN[4];
    #pragma unroll
    for (int mr = 0; mr < 5; ++mr)
        aC[mr] = *(const bf16x8*)(wthr + mr*512);
    __syncthreads();

    for (int c = 0; c < 10; ++c) {
        const char* buf = (const char*)lds + (c&1)*17408;
        // prefetch next input chunk into the other buffer
        if (c < 9) {
            #pragma unroll
            for (int s = 0; s < 3; ++s)
                if (s < nslot) gl_lds16(ga[s], (u16*)((char*)lds + ((c&1)^1)*17408 + js[s]*1024));
            #pragma unroll
            for (int s = 0; s < 3; ++s) ga[s] += 32;
        }
        // bb for tap 0
        #pragma unroll
        for (int nf = 0; nf < 4; ++nf) {
            int col = nf*16 + l15;       // kx=0
            int boff = wrow*4224 + col*64 + ((l4 ^ ((col>>1)&3))<<4);
            bbC[nf] = *(const bf16x8*)(buf + boff);
        }
        #pragma unroll
        for (int t = 0; t < 9; ++t) {
            int ky = t/3, kx = t - ky*3;
            // prefetch next tap's operands (or next chunk's tap0 A)
            if (t < 8) {
                #pragma unroll
                for (int mr = 0; mr < 5; ++mr)
                    aN[mr] = *(const bf16x8*)(wthr + (size_t)(c*9 + t + 1)*CH*32 + mr*512);
                int kyn = (t+1)/3, kxn = (t+1) - kyn*3;
                int rowbase_n = (wrow + kyn) * 4224;
                #pragma unroll
                for (int nf = 0; nf < 4; ++nf) {
                    int col = nf*16 + l15 + kxn;
                    int boff = rowbase_n + col*64 + ((l4 ^ ((col>>1)&3))<<4);
                    bbN[nf] = *(const bf16x8*)(buf + boff);
                }
            } else if (c < 9) {
                #pragma unroll
                for (int mr = 0; mr < 5; ++mr)
                    aN[mr] = *(const bf16x8*)(wthr + (size_t)((c+1)*9)*CH*32 + mr*512);
            }
            // MFMA cluster on current operands
            #pragma unroll
            for (int mr = 0; mr < 5; ++mr)
                #pragma unroll
                for (int nf = 0; nf < 4; ++nf)
                    acc[mr][nf] = __builtin_amdgcn_mfma_f32_16x16x32_bf16(
                        aC[mr], bbC[nf], acc[mr][nf], 0, 0, 0);
            // rotate
            if (t < 8) {
                #pragma unroll
                for (int mr = 0; mr < 5; ++mr) aC[mr] = aN[mr];
                #pragma unroll
                for (int nf = 0; nf < 4; ++nf) bbC[nf] = bbN[nf];
            } else if (c < 9) {
                #pragma unroll
                for (int mr = 0; mr < 5; ++mr) aC[mr] = aN[mr];
            }
        }
        __syncthreads();   // prefetch (input + A) drained; buffers swap
    }

    int y = y0 + wrow;
    #pragma unroll
    for (int mr = 0; mr < 5; ++mr) {
        #pragma unroll
        for (int r = 0; r < 4; ++r) {
            int co = co0w + mr*16 + l4*4 + r;
            float bv = bias[co];
            float* ob = out + ((size_t)(b*CH + co))*HW + y*64;
            #pragma unroll
            for (int nf = 0; nf < 4; ++nf) {
                int xx = nf*16 + l15;
                ob[xx] = fmaxf(acc[mr][nf][r] + bv, 0.f);
            }
        }
    }
}

extern "C" void kernel_launch(void* const* d_in, const int* in_sizes, int n_in,
                              void* d_out, int out_size, void* d_ws, size_t ws_size,
                              hipStream_t stream) {
    const float* x  = (const float*)d_in[0];
    const float* Ks = (const float*)d_in[1];
    const float* Kt = (const float*)d_in[2];
    const float* ps = (const float*)d_in[3];
    const float* pt = (const float*)d_in[4];
    const float* cw = (const float*)d_in[5];
    const float* cb = (const float*)d_in[6];
    float* out = (float*)d_out;
    char* ws = (char*)d_ws;
    float* zp = (float*)(ws + ZP_OFF);
    u16*   st = (u16*)(ws + SAMP_OFF);
    u16*   wt = (u16*)(ws + WT_OFF);

    k_wprep<<<(9*CH*CH + 255)/256, 256, 0, stream>>>(cw, wt, zp);
    k_sample8<<<dim3(CH/8, BATCH), 256, 0, stream>>>(x, Ks, Kt, ps, pt, st);
    k_conv<<<dim3(32, BATCH), 512, 0, stream>>>(st, wt, cb, zp, out);
}

// Round 9
// 92.879 us; speedup vs baseline: 44.4353x; 1.2560x over previous
//
#include <hip/hip_runtime.h>
#include <math.h>

#define BATCH 8
#define CH 320
#define HW 4096

typedef unsigned short u16;
typedef __attribute__((ext_vector_type(8))) short bf16x8;
typedef __attribute__((ext_vector_type(8))) unsigned short u16x8;
typedef __attribute__((ext_vector_type(4))) float f32x4;
typedef __attribute__((ext_vector_type(4))) float float4v;

// ws byte layout
#define ZP_OFF 0                 // 1 KB zero page (gload_lds OOB target)
#define SAMP_OFF 788480          // bf16 [b][4096][320] = 20,971,520 B
#define WT_OFF 21760000          // bf16 [chunk][tap][co][32] = 1,843,200 B

// k_conv LDS layout
#define IBUF_BYTES 17408
#define A_OFF (2*IBUF_BYTES)         // 34816
#define APHASE 61440                 // 3 taps x 320co x 32ci x 2B
#define LDS_TOTAL (A_OFF + 2*APHASE) // 157696 B (<= 160 KiB)

__device__ __forceinline__ u16 f2bf(float f) {
    union { float f; unsigned u; } v; v.f = f;
    unsigned r = v.u + 0x7fffu + ((v.u >> 16) & 1u);   // RNE
    return (u16)(r >> 16);
}
__device__ __forceinline__ float bf2f(u16 h) {
    union { unsigned u; float f; } v; v.u = ((unsigned)h) << 16;
    return v.f;
}
__device__ __forceinline__ void gl_lds16(const void* g, void* l) {
    __builtin_amdgcn_global_load_lds(
        (const __attribute__((address_space(1))) unsigned*)g,
        (__attribute__((address_space(3))) unsigned*)l, 16, 0, 0);
}

__device__ __forceinline__ void rodrigues3(float rv0, float rv1, float rv2, float* R) {
    float theta = sqrtf(rv0*rv0 + rv1*rv1 + rv2*rv2);
    float it = 1.0f / fmaxf(theta, 1e-12f);
    float r0 = rv0*it, r1 = rv1*it, r2 = rv2*it;
    float c = cosf(theta), s = sinf(theta), o = 1.0f - c;
    R[0]=c+o*r0*r0;    R[1]=o*r0*r1-s*r2; R[2]=o*r0*r2+s*r1;
    R[3]=o*r1*r0+s*r2; R[4]=c+o*r1*r1;    R[5]=o*r1*r2-s*r0;
    R[6]=o*r2*r0-s*r1; R[7]=o*r2*r1+s*r0; R[8]=c+o*r2*r2;
    if (theta < 1e-6f) { R[0]=1;R[1]=0;R[2]=0;R[3]=0;R[4]=1;R[5]=0;R[6]=0;R[7]=0;R[8]=1; }
}

__device__ __forceinline__ void inv3(const float* M, float* o) {
    float a=M[0],b=M[1],c=M[2],d=M[3],e=M[4],f=M[5],g=M[6],h=M[7],i=M[8];
    float A = e*i - f*h, B = f*g - d*i, C = d*h - e*g;
    float id = 1.0f / (a*A + b*B + c*C);
    o[0]=A*id;         o[1]=(c*h-b*i)*id; o[2]=(b*f-c*e)*id;
    o[3]=B*id;         o[4]=(a*i-c*g)*id; o[5]=(c*d-a*f)*id;
    o[6]=C*id;         o[7]=(b*g-a*h)*id; o[8]=(a*e-b*d)*id;
}

// fundamental matrix for batch b (computed redundantly per thread; ~300 VALU ops)
__device__ void compute_F(const float* Ks, const float* Kt, const float* ps,
                          const float* pt, int b, float* Fm) {
    float Rs[9], Rt[9];
    rodrigues3(ps[b*6+0], ps[b*6+1], ps[b*6+2], Rs);
    rodrigues3(pt[b*6+0], pt[b*6+1], pt[b*6+2], Rt);
    float Rr[9];
    #pragma unroll
    for (int i = 0; i < 3; ++i)
      #pragma unroll
      for (int k = 0; k < 3; ++k)
        Rr[i*3+k] = Rs[i*3+0]*Rt[k*3+0] + Rs[i*3+1]*Rt[k*3+1] + Rs[i*3+2]*Rt[k*3+2];
    float tt0 = pt[b*6+3], tt1 = pt[b*6+4], tt2 = pt[b*6+5];
    float tr0 = ps[b*6+3] - (Rr[0]*tt0 + Rr[1]*tt1 + Rr[2]*tt2);
    float tr1 = ps[b*6+4] - (Rr[3]*tt0 + Rr[4]*tt1 + Rr[5]*tt2);
    float tr2 = ps[b*6+5] - (Rr[6]*tt0 + Rr[7]*tt1 + Rr[8]*tt2);
    float E[9];
    #pragma unroll
    for (int j = 0; j < 3; ++j) {
        E[0*3+j] = -tr2*Rr[1*3+j] + tr1*Rr[2*3+j];
        E[1*3+j] =  tr2*Rr[0*3+j] - tr0*Rr[2*3+j];
        E[2*3+j] = -tr1*Rr[0*3+j] + tr0*Rr[1*3+j];
    }
    float iKs[9], iKt[9];
    inv3(Ks + b*9, iKs);
    inv3(Kt + b*9, iKt);
    float T[9];
    #pragma unroll
    for (int i = 0; i < 3; ++i)
      #pragma unroll
      for (int k = 0; k < 3; ++k)
        T[i*3+k] = iKt[0*3+i]*E[0*3+k] + iKt[1*3+i]*E[1*3+k] + iKt[2*3+i]*E[2*3+k];
    #pragma unroll
    for (int i = 0; i < 3; ++i)
      #pragma unroll
      for (int l = 0; l < 3; ++l)
        Fm[i*3 + l] = T[i*3+0]*iKs[0*3+l] + T[i*3+1]*iKs[1*3+l] + T[i*3+2]*iKs[2*3+l];
}

// weights: OIHW fp32 -> [ci_chunk][tap][co][ci_in_chunk] bf16 + zero-page init
__global__ __launch_bounds__(256) void k_wprep(const float* __restrict__ wsrc,
                                               u16* __restrict__ wt,
                                               float* __restrict__ zp) {
    int idx = blockIdx.x*256 + threadIdx.x;
    if (blockIdx.x == 0) zp[threadIdx.x] = 0.0f;   // 1 KB zero page
    if (idx >= 9*CH*CH) return;
    int cl = idx & 31;
    int r  = idx >> 5;
    int co = r % CH;
    int q  = r / CH;
    int t  = q % 9;       // tap
    int c  = q / 9;       // ci chunk
    int ci = c*32 + cl;
    wt[idx] = f2bf(wsrc[((size_t)co*CH + ci)*9 + t]);
}

// fused: fundamental matrix + epipolar line + bilinear sample (3 pts, mean).
// 8 channels/block; output channel-last bf16 [b][pix][320]
__global__ __launch_bounds__(256) void k_sample8(const float* __restrict__ x,
                                                 const float* __restrict__ Ks,
                                                 const float* __restrict__ Kt,
                                                 const float* __restrict__ ps,
                                                 const float* __restrict__ pt,
                                                 u16* __restrict__ st) {
    __shared__ u16 pl[HW*8];   // 64 KB, [pix][8ch] bf16
    int cg = blockIdx.x, b = blockIdx.y;
    int tid = threadIdx.x;
    const float* xb = x + ((size_t)b*CH + cg*8)*HW;
    const float4v* xb4 = (const float4v*)xb;
    #pragma unroll
    for (int it = 0; it < 4; ++it) {
        int i0 = (it*256 + tid)*4;
        float4v v[8];
        #pragma unroll
        for (int c = 0; c < 8; ++c) v[c] = xb4[c*(HW/4) + it*256 + tid];
        #pragma unroll
        for (int j = 0; j < 4; ++j) {
            u16x8 o;
            #pragma unroll
            for (int c = 0; c < 8; ++c) o[c] = f2bf(v[c][j]);
            *(u16x8*)(pl + (i0 + j)*8) = o;
        }
    }
    float Fm[9];
    compute_F(Ks, Kt, ps, pt, b, Fm);
    __syncthreads();
    const float EPS = 1e-10f, W1 = 63.0f, H1 = 63.0f;
    for (int k = tid; k < HW; k += 256) {
        float px = (float)(k & 63);
        float py = (float)(k >> 6);
        float a  = Fm[0]*px + Fm[3]*py + Fm[6];
        float bb = Fm[1]*px + Fm[4]*py + Fm[7];
        float c  = Fm[2]*px + Fm[5]*py + Fm[8];
        float x1 = fminf(fmaxf(-c/(a+EPS), 0.0f), W1);
        float x2 = fminf(fmaxf(-(bb*H1+c)/(a+EPS), 0.0f), W1);
        float y1 = fminf(fmaxf(-c/(bb+EPS), 0.0f), H1);
        float y2 = fminf(fmaxf(-(a*W1+c)/(bb+EPS), 0.0f), H1);
        float sxs[3], sys[3];
        sxs[0] = x1; sys[0] = y1;
        sxs[1] = 0.5f*(x1+x2); sys[1] = 0.5f*(y1+y2);
        sxs[2] = x2; sys[2] = y2;
        float acc[8];
        #pragma unroll
        for (int c2 = 0; c2 < 8; ++c2) acc[c2] = 0.f;
        #pragma unroll
        for (int s = 0; s < 3; ++s) {
            float sx = sxs[s], sy = sys[s];
            float fx = floorf(sx), fy = floorf(sy);
            float wx = sx-fx, wy = sy-fy;
            int x0 = (int)fx, y0 = (int)fy;
            int x1i = min(x0+1,63), y1i = min(y0+1,63);
            u16x8 g00 = *(const u16x8*)(pl + (y0*64+x0)*8);
            u16x8 g10 = *(const u16x8*)(pl + (y0*64+x1i)*8);
            u16x8 g01 = *(const u16x8*)(pl + (y1i*64+x0)*8);
            u16x8 g11 = *(const u16x8*)(pl + (y1i*64+x1i)*8);
            float w00=(1.f-wx)*(1.f-wy), w10=wx*(1.f-wy), w01=(1.f-wx)*wy, w11=wx*wy;
            #pragma unroll
            for (int c2 = 0; c2 < 8; ++c2)
                acc[c2] += w00*bf2f(g00[c2]) + w10*bf2f(g10[c2])
                         + w01*bf2f(g01[c2]) + w11*bf2f(g11[c2]);
        }
        u16x8 o;
        #pragma unroll
        for (int c2 = 0; c2 < 8; ++c2) o[c2] = f2bf(acc[c2]*(1.f/3.f));
        *(u16x8*)(st + ((size_t)b*HW + k)*CH + cg*8) = o;
    }
}

// implicit-GEMM conv, A(weights) staged in LDS.
// Block = 512 thr (8 waves) = 320co x 128pix (2 rows); grid 256 = 1 block/CU.
// 30 phases (10 ci-chunks x 3 ky). Per phase: stage next phase's A (3 taps,
// 61440B, 60 gl_lds insts) into the other A buffer; at ky==0 also stage next
// input chunk; compute 3 kx x {4 B ds_reads + 5 A ds_reads + 20 MFMA}/wave.
// A LDS swizzle: granule slot k = (lane&3)^((lane>>3)&3) on the SOURCE side
// (pure lane constant -> single address reg); read slot = l4^((l15>>1)&3)
// spreads 16 lanes over all 8 bank-quads exactly 2x -> conflict-free.
__global__ __launch_bounds__(512, 1) void k_conv(const u16* __restrict__ st,
                                                 const u16* __restrict__ wt,
                                                 const float* __restrict__ bias,
                                                 const float* __restrict__ zp,
                                                 float* __restrict__ out) {
    __shared__ __align__(16) char lds[LDS_TOTAL];
    int rowblk = blockIdx.x;      // 0..31
    int b      = blockIdx.y;
    int y0 = rowblk*2;
    int lane = threadIdx.x & 63;
    int w = threadIdx.x >> 6;     // 0..7
    int wrow = w & 1;
    int co0w = (w >> 1) * 80;
    int l15 = lane & 15, l4 = lane >> 4;

    // ---- input staging: 1056 granules over 17 insts; wave w: slots {w, 8+w},
    // wave 0 additionally slot 16 (granules >=1056 OOB -> zero page).
    const u16* ga[3];
    int js[3];
    #pragma unroll
    for (int s = 0; s < 3; ++s) {
        int j = (s < 2) ? (s*8 + w) : 16;
        js[s] = j;
        int g = j*64 + lane;
        int row_l = g/264;
        int rem = g - row_l*264;
        int col = rem >> 2;
        int slot = rem & 3;
        int ks = slot ^ ((col>>1)&3);
        int yy = y0 - 1 + row_l;
        int xx = col - 1;
        bool oob = (g >= 1056) | (yy < 0) | (yy > 63) | (xx < 0) | (xx > 63);
        int yc = min(max(yy,0),63), xc = min(max(xx,0),63);
        const u16* p = st + (((size_t)b*HW) + yc*64 + xc)*CH + ks*8;
        ga[s] = oob ? (const u16*)zp : p;
    }
    int nslot = (w == 0) ? 3 : 2;

    // ---- A staging: phase region = 61440B; inst j = s*8+w (j<60) covers 1024B.
    // src(p, j, lane) = wt + p*61440 + j*1024 + (lane>>2)*64 + ((lane&3)^((lane>>3)&3))*16
    int alaneoff = ((lane>>2)<<6) + ((((lane&3) ^ ((lane>>3)&3))) << 4);
    const char* asrc = (const char*)wt + alaneoff;   // advances by APHASE per phase

    // ---- A read: byte = A_OFF + buf*APHASE + kx*20480 + mr*1024 + ard_off
    int ard_off = (co0w + l15)*64 + ((l4 ^ ((l15>>1)&3)) << 4);

    f32x4 acc[5][4];
    #pragma unroll
    for (int mr = 0; mr < 5; ++mr)
        #pragma unroll
        for (int nf = 0; nf < 4; ++nf) acc[mr][nf] = (f32x4){0.f,0.f,0.f,0.f};

    // ---- prologue: stage input chunk0 + A phase0
    #pragma unroll
    for (int s = 0; s < 3; ++s)
        if (s < nslot) gl_lds16(ga[s], lds + js[s]*1024);
    #pragma unroll
    for (int s = 0; s < 3; ++s) ga[s] += 32;
    #pragma unroll
    for (int s = 0; s < 8; ++s) {
        int j = s*8 + w;
        if (j < 60) gl_lds16(asrc + j*1024, lds + A_OFF + j*1024);
    }
    asrc += APHASE;
    __syncthreads();

    for (int c = 0; c < 10; ++c) {
        const char* ibuf = lds + (c&1)*IBUF_BYTES;
        #pragma unroll
        for (int ky = 0; ky < 3; ++ky) {
            int p = c*3 + ky;
            // stage A for phase p+1 into the other A buffer
            if (p < 29) {
                char* adst = lds + A_OFF + ((p+1)&1)*APHASE;
                #pragma unroll
                for (int s = 0; s < 8; ++s) {
                    int j = s*8 + w;
                    if (j < 60) gl_lds16(asrc + j*1024, adst + j*1024);
                }
                asrc += APHASE;
            }
            // stage next input chunk once per chunk
            if (ky == 0 && c < 9) {
                char* idst = lds + ((c&1)^1)*IBUF_BYTES;
                #pragma unroll
                for (int s = 0; s < 3; ++s)
                    if (s < nslot) gl_lds16(ga[s], idst + js[s]*1024);
                #pragma unroll
                for (int s = 0; s < 3; ++s) ga[s] += 32;
            }
            // compute phase p from Abuf[p&1] + ibuf
            const char* abuf = lds + A_OFF + (p&1)*APHASE;
            int rowbase = (wrow + ky) * 4224;
            #pragma unroll
            for (int kx = 0; kx < 3; ++kx) {
                bf16x8 bb[4];
                #pragma unroll
                for (int nf = 0; nf < 4; ++nf) {
                    int col = nf*16 + l15 + kx;
                    int boff = rowbase + col*64 + ((l4 ^ ((col>>1)&3))<<4);
                    bb[nf] = *(const bf16x8*)(ibuf + boff);
                }
                bf16x8 a[5];
                #pragma unroll
                for (int mr = 0; mr < 5; ++mr)
                    a[mr] = *(const bf16x8*)(abuf + kx*20480 + mr*1024 + ard_off);
                #pragma unroll
                for (int mr = 0; mr < 5; ++mr)
                    #pragma unroll
                    for (int nf = 0; nf < 4; ++nf)
                        acc[mr][nf] = __builtin_amdgcn_mfma_f32_16x16x32_bf16(
                            a[mr], bb[nf], acc[mr][nf], 0, 0, 0);
            }
            __syncthreads();   // A(p+1)/input staging drained; buffers swap
        }
    }

    int y = y0 + wrow;
    #pragma unroll
    for (int mr = 0; mr < 5; ++mr) {
        #pragma unroll
        for (int r = 0; r < 4; ++r) {
            int co = co0w + mr*16 + l4*4 + r;
            float bv = bias[co];
            float* ob = out + ((size_t)(b*CH + co))*HW + y*64;
            #pragma unroll
            for (int nf = 0; nf < 4; ++nf) {
                int xx = nf*16 + l15;
                ob[xx] = fmaxf(acc[mr][nf][r] + bv, 0.f);
            }
        }
    }
}

extern "C" void kernel_launch(void* const* d_in, const int* in_sizes, int n_in,
                              void* d_out, int out_size, void* d_ws, size_t ws_size,
                              hipStream_t stream) {
    const float* x  = (const float*)d_in[0];
    const float* Ks = (const float*)d_in[1];
    const float* Kt = (const float*)d_in[2];
    const float* ps = (const float*)d_in[3];
    const float* pt = (const float*)d_in[4];
    const float* cw = (const float*)d_in[5];
    const float* cb = (const float*)d_in[6];
    float* out = (float*)d_out;
    char* ws = (char*)d_ws;
    float* zp = (float*)(ws + ZP_OFF);
    u16*   st = (u16*)(ws + SAMP_OFF);
    u16*   wt = (u16*)(ws + WT_OFF);

    k_wprep<<<(9*CH*CH + 255)/256, 256, 0, stream>>>(cw, wt, zp);
    k_sample8<<<dim3(CH/8, BATCH), 256, 0, stream>>>(x, Ks, Kt, ps, pt, st);
    k_conv<<<dim3(32, BATCH), 512, 0, stream>>>(st, wt, cb, zp, out);
}